// Round 13
// baseline (1265.068 us; speedup 1.0000x reference)
//
#include <hip/hip_runtime.h>
#include <stdint.h>

#define TOK 2048
#define HID 4096
#define VOC 32000
#define NKT (HID / 64)  // 64 K-tiles of BK=64
#define NNT (VOC / 256) // 125 N-tiles
#define MREF 16.0f      // fixed LSE reference: exp(z-16) safe for |z| << 70

typedef __attribute__((ext_vector_type(4))) float f32x4;
typedef __attribute__((ext_vector_type(8))) short bf16x8;
typedef __attribute__((ext_vector_type(8))) unsigned short u16x8;

__device__ __forceinline__ float bf2f(unsigned short u) {
  return __uint_as_float(((unsigned int)u) << 16);
}
__device__ __forceinline__ unsigned short f2bf(float f) {
  unsigned int u = __float_as_uint(f);
  u += 0x7FFFu + ((u >> 16) & 1u);  // round-to-nearest-even
  return (unsigned short)(u >> 16);
}

// ---------------- all four casts in one launch (4 grid-stride regions) ----------------
__device__ __forceinline__ void cast8(const float* __restrict__ in,
                                      unsigned short* __restrict__ out) {
  const float4 v0 = *(const float4*)(in);
  const float4 v1 = *(const float4*)(in + 4);
  union { ushort s[8]; uint4 u; } o;
  o.s[0] = f2bf(v0.x); o.s[1] = f2bf(v0.y); o.s[2] = f2bf(v0.z); o.s[3] = f2bf(v0.w);
  o.s[4] = f2bf(v1.x); o.s[5] = f2bf(v1.y); o.s[6] = f2bf(v1.z); o.s[7] = f2bf(v1.w);
  *(uint4*)(out) = o.u;
}

__global__ __launch_bounds__(256) void cast_all(const float* __restrict__ a, unsigned short* __restrict__ oa, long na,
                                                const float* __restrict__ b, unsigned short* __restrict__ ob, long nb,
                                                const float* __restrict__ c, unsigned short* __restrict__ oc, long nc,
                                                const float* __restrict__ d, unsigned short* __restrict__ od, long nd,
                                                float* __restrict__ out0) {
  if (blockIdx.x == 0 && threadIdx.x == 0) out0[0] = 0.f;  // init for jsd atomicAdd
  const long base = ((long)blockIdx.x * 256 + threadIdx.x) * 8;
  const long stride = (long)gridDim.x * 256 * 8;
  for (long i = base; i < na; i += stride) cast8(a + i, oa + i);
  for (long i = base; i < nb; i += stride) cast8(b + i, ob + i);
  for (long i = base; i < nc; i += stride) cast8(c + i, oc + i);
  for (long i = base; i < nd; i += stride) cast8(d + i, od + i);
}

// ---------------- async global -> LDS (16B/lane) ----------------
__device__ __forceinline__ void gload_lds16(const void* g, void* l) {
  __builtin_amdgcn_global_load_lds(
      (const __attribute__((address_space(1))) unsigned int*)(uintptr_t)g,
      (__attribute__((address_space(3))) unsigned int*)(uintptr_t)l,
      16, 0, 0);
}

// ---------------- dual 256x256 bf16 GEMM (one dispatch) + fixed-ref LSE epilogue ----
// Blocks 0..999 (after XCD swizzle) -> student, 1000..1999 -> teacher.
// K-loop = r10-r12 measured-best schedule, with stageB(u+1) hoisted to tile top
// (gloads dependency-free; HBM requests in flight before the ds_read burst; WAR on
// buf nxt cleared at tile u-1's MID barrier, two barriers upstream).
__global__ __launch_bounds__(512, 2) void gemm256(const unsigned short* __restrict__ A0,
                                                  const unsigned short* __restrict__ B0,
                                                  unsigned short* __restrict__ C0,
                                                  float2* __restrict__ pp0,
                                                  const unsigned short* __restrict__ A1,
                                                  const unsigned short* __restrict__ B1,
                                                  unsigned short* __restrict__ C1,
                                                  float2* __restrict__ pp1) {
  __shared__ unsigned short As[2][2][128 * 64];
  __shared__ unsigned short Bs[2][2][128 * 64];
  const int tid = threadIdx.x;
  const int w = tid >> 6;
  const int l = tid & 63;
  const int wr = w >> 2;   // 0..1 (M half)
  const int wc = w & 3;    // 0..3 (N quarter)

  // T1: XCD swizzle over the merged 2000-block grid (2000 % 8 == 0).
  const int bid = blockIdx.x;
  const int cpx = gridDim.x >> 3;                 // 250
  int swz = (bid & 7) * cpx + (bid >> 3);
  const int which = swz >= (TOK / 256) * NNT;     // >= 1000 -> teacher
  if (which) swz -= (TOK / 256) * NNT;
  const int mt = swz & 7;                         // 8 M-tiles
  const int nt = swz >> 3;                        // 125 N-tiles

  const unsigned short* __restrict__ A = which ? A1 : A0;
  const unsigned short* __restrict__ B = which ? B1 : B0;
  unsigned short* __restrict__ C = which ? C1 : C0;
  float2* __restrict__ pp = which ? pp1 : pp0;

  const size_t Abase = (size_t)mt * 256 * HID;
  const size_t Bbase = (size_t)nt * 256 * HID;

  f32x4 acc[8][4] = {};

  const int r8 = l >> 3;
  const int scol = ((l & 7) ^ r8) << 3;  // swizzled source column (elements)

  auto stageA = [&](int half, int v) {
    const unsigned short* src = A + Abase + (size_t)half * 128 * HID + (size_t)v * 64 + scol;
#pragma unroll
    for (int i = 0; i < 2; ++i) {
      const int c = 2 * w + i;
      gload_lds16(src + (size_t)(c * 8 + r8) * HID, &As[v & 1][half][c * 512]);
    }
  };
  auto stageB = [&](int half, int v) {
    const unsigned short* src = B + Bbase + (size_t)half * 128 * HID + (size_t)v * 64 + scol;
#pragma unroll
    for (int i = 0; i < 2; ++i) {
      const int c = 2 * w + i;
      gload_lds16(src + (size_t)(c * 8 + r8) * HID, &Bs[v & 1][half][c * 512]);
    }
  };

  // prologue: tile0 all halves + tile1 A halves; retire tile0's 8 (keep A(1) in flight)
  stageA(0, 0); stageA(1, 0); stageB(0, 0); stageB(1, 0);
  stageA(0, 1); stageA(1, 1);
  asm volatile("s_waitcnt vmcnt(4)" ::: "memory");
  __builtin_amdgcn_s_barrier();

  const int lr = l & 15;
  const int c0 = ((l >> 4) << 4) ^ ((lr & 7) << 4);  // byte col for kk=0
  const int c1 = c0 ^ 64;                            // byte col for kk=32
  const int brow = (wc & 1) * 64;                    // wave's N-row base in its B half

#pragma unroll 2
  for (int u = 0; u < NKT; ++u) {
    const int cur = u & 1;
    const char* Ah = (const char*)&As[cur][wr][0];
    const char* Bh = (const char*)&Bs[cur][wc >> 1][0];
    bf16x8 a0[8], a1[8], b0[4], b1[4];

    // stage B(u+1) FIRST (dependency-free; WAR cleared at u-1's mid barrier)
    if (u + 1 < NKT) { stageB(0, u + 1); stageB(1, u + 1); }

    // ---- issue all 24 ds_reads (compiler schedules + counted auto-lgkmcnt) ----
#pragma unroll
    for (int mf = 0; mf < 4; ++mf) {
      const int rb = (mf * 16 + lr) << 7;
      a0[2 * mf]     = *(const bf16x8*)(Ah + rb + c0);
      a0[2 * mf + 1] = *(const bf16x8*)(Ah + rb + c1);
    }
#pragma unroll
    for (int nf = 0; nf < 2; ++nf) {
      const int rb = (brow + nf * 16 + lr) << 7;
      b0[2 * nf]     = *(const bf16x8*)(Bh + rb + c0);
      b0[2 * nf + 1] = *(const bf16x8*)(Bh + rb + c1);
    }
#pragma unroll
    for (int mf = 0; mf < 4; ++mf) {
      const int rb = ((mf + 4) * 16 + lr) << 7;
      a1[2 * mf]     = *(const bf16x8*)(Ah + rb + c0);
      a1[2 * mf + 1] = *(const bf16x8*)(Ah + rb + c1);
    }
#pragma unroll
    for (int nf = 0; nf < 2; ++nf) {
      const int rb = (brow + (nf + 2) * 16 + lr) << 7;
      b1[2 * nf]     = *(const bf16x8*)(Bh + rb + c0);
      b1[2 * nf + 1] = *(const bf16x8*)(Bh + rb + c1);
    }

    __builtin_amdgcn_s_setprio(1);
    // q(0,0), q(1,0), q(1,1): 48 MFMA
#pragma unroll
    for (int mf = 0; mf < 4; ++mf)
#pragma unroll
      for (int nf = 0; nf < 2; ++nf) {
        acc[mf][nf] = __builtin_amdgcn_mfma_f32_16x16x32_bf16(a0[2 * mf], b0[2 * nf], acc[mf][nf], 0, 0, 0);
        acc[mf][nf] = __builtin_amdgcn_mfma_f32_16x16x32_bf16(a0[2 * mf + 1], b0[2 * nf + 1], acc[mf][nf], 0, 0, 0);
      }
#pragma unroll
    for (int mf = 0; mf < 4; ++mf)
#pragma unroll
      for (int nf = 0; nf < 2; ++nf) {
        acc[4 + mf][nf] = __builtin_amdgcn_mfma_f32_16x16x32_bf16(a1[2 * mf], b0[2 * nf], acc[4 + mf][nf], 0, 0, 0);
        acc[4 + mf][nf] = __builtin_amdgcn_mfma_f32_16x16x32_bf16(a1[2 * mf + 1], b0[2 * nf + 1], acc[4 + mf][nf], 0, 0, 0);
      }
#pragma unroll
    for (int mf = 0; mf < 4; ++mf)
#pragma unroll
      for (int nf = 0; nf < 2; ++nf) {
        acc[4 + mf][2 + nf] = __builtin_amdgcn_mfma_f32_16x16x32_bf16(a1[2 * mf], b1[2 * nf], acc[4 + mf][2 + nf], 0, 0, 0);
        acc[4 + mf][2 + nf] = __builtin_amdgcn_mfma_f32_16x16x32_bf16(a1[2 * mf + 1], b1[2 * nf + 1], acc[4 + mf][2 + nf], 0, 0, 0);
      }
    __builtin_amdgcn_s_setprio(0);

    // all reads of this tile's buffers drained chip-wide before stageA(u+2)
    asm volatile("s_waitcnt lgkmcnt(0)" ::: "memory");
    __builtin_amdgcn_s_barrier();

    if (u + 2 < NKT) { stageA(0, u + 2); stageA(1, u + 2); }

    __builtin_amdgcn_s_setprio(1);
    // q(0,1): register-only (a0, b1 held) — covers stage-issue + vmcnt shadow
#pragma unroll
    for (int mf = 0; mf < 4; ++mf)
#pragma unroll
      for (int nf = 0; nf < 2; ++nf) {
        acc[mf][2 + nf] = __builtin_amdgcn_mfma_f32_16x16x32_bf16(a0[2 * mf], b1[2 * nf], acc[mf][2 + nf], 0, 0, 0);
        acc[mf][2 + nf] = __builtin_amdgcn_mfma_f32_16x16x32_bf16(a0[2 * mf + 1], b1[2 * nf + 1], acc[mf][2 + nf], 0, 0, 0);
      }
    __builtin_amdgcn_s_setprio(0);

    if (u + 2 < NKT) {
      asm volatile("s_waitcnt vmcnt(4)" ::: "memory");  // retire B(u+1)+A(u+1), keep A(u+2)
      __builtin_amdgcn_s_barrier();
    } else if (u + 1 < NKT) {
      asm volatile("s_waitcnt vmcnt(0)" ::: "memory");  // u=62: drain A(63)+B(63)
      __builtin_amdgcn_s_barrier();
    }
  }

  // ---- epilogue: C write + fixed-ref row-sum of exp(z-MREF), fused ----
  __syncthreads();  // all K-loop LDS reads done; reuse As as reduction scratch
  float* red = (float*)&As[0][0][0];  // [256 rows][stride 5] (pad -> conflict-free)
  const int lg = (l >> 4) * 4;
#pragma unroll
  for (int mf = 0; mf < 8; ++mf)
#pragma unroll
    for (int r = 0; r < 4; ++r) {
      const int rowl = wr * 128 + mf * 16 + lg + r;
      const int row = mt * 256 + rowl;
      float vsum = 0.f;
#pragma unroll
      for (int nf = 0; nf < 4; ++nf) {
        const unsigned short cb = f2bf(acc[mf][nf][r]);
        C[(size_t)row * VOC + nt * 256 + wc * 64 + nf * 16 + lr] = cb;
        vsum += __expf(bf2f(cb) - MREF);
      }
#pragma unroll
      for (int off = 1; off < 16; off <<= 1) vsum += __shfl_xor(vsum, off);
      if (lr == 0) red[rowl * 5 + wc] = vsum;
    }
  __syncthreads();
  if (tid < 256) {
    const float s = red[tid * 5] + red[tid * 5 + 1] + red[tid * 5 + 2] + red[tid * 5 + 3];
    pp[(size_t)(mt * 256 + tid) * NNT + nt] = make_float2(MREF, s);
  }
}

// ---------------- per-token JSD (single pass) + direct atomic accumulation ----------------
__global__ __launch_bounds__(256) void jsd_kernel(const unsigned short* __restrict__ SL,
                                                  const unsigned short* __restrict__ TL,
                                                  const float2* __restrict__ ppS,
                                                  const float2* __restrict__ ppT,
                                                  float* __restrict__ out) {
  const int t = blockIdx.x;
  const int tid = threadIdx.x;
  const unsigned short* srow = SL + (size_t)t * VOC;
  const unsigned short* trow = TL + (size_t)t * VOC;

  // all partial maxima are MREF -> exact additive merge, no exp chains
  float ss = 0.f, st = 0.f;
  if (tid < NNT) {
    ss = ppS[(size_t)t * NNT + tid].y;
    st = ppT[(size_t)t * NNT + tid].y;
  }
#pragma unroll
  for (int off = 32; off > 0; off >>= 1) {
    ss += __shfl_xor(ss, off);
    st += __shfl_xor(st, off);
  }
  __shared__ float red[4][2];
  const int w = tid >> 6;
  if ((tid & 63) == 0) { red[w][0] = ss; red[w][1] = st; }
  __syncthreads();
  const float Ss = red[0][0] + red[1][0] + red[2][0] + red[3][0];
  const float St = red[0][1] + red[1][1] + red[2][1] + red[3][1];
  const float logZs = MREF + __logf(Ss);
  const float logZt = MREF + __logf(St);

  // single pass: jsd = 0.5*[p*(lp-lm) + q*(lq-lm)], lm = log(0.5)+logaddexp(lp,lq)
  float acc = 0.f;
  for (int c = tid; c < VOC / 8; c += 256) {
    u16x8 vs = *(const u16x8*)(srow + c * 8);
    u16x8 vt = *(const u16x8*)(trow + c * 8);
#pragma unroll
    for (int j = 0; j < 8; ++j) {
      float lq = bf2f(vs[j]) - logZs;
      float lp = bf2f(vt[j]) - logZt;
      float mx = fmaxf(lp, lq);
      float d = fabsf(lp - lq);
      float lm = mx + __logf(1.f + __expf(-d)) - 0.69314718f;
      acc += __expf(lp) * (lp - lm) + __expf(lq) * (lq - lm);
    }
  }
  acc *= 0.5f;
#pragma unroll
  for (int off = 32; off > 0; off >>= 1) acc += __shfl_xor(acc, off);
  __shared__ float red2[4];
  if ((tid & 63) == 0) red2[w] = acc;
  __syncthreads();
  if (tid == 0)
    atomicAdd(out, (red2[0] + red2[1] + red2[2] + red2[3]) * (1.0f / TOK));
}

// ---------------- launch ----------------
extern "C" void kernel_launch(void* const* d_in, const int* in_sizes, int n_in,
                              void* d_out, int out_size, void* d_ws, size_t ws_size,
                              hipStream_t stream) {
  const float* sIn = (const float*)d_in[0];
  const float* tIn = (const float*)d_in[1];
  const float* sW  = (const float*)d_in[2];
  const float* tW  = (const float*)d_in[3];
  float* out = (float*)d_out;

  unsigned short* ws = (unsigned short*)d_ws;
  unsigned short* sA  = ws;                        // 2048*4096 bf16
  unsigned short* tA  = sA  + (long)TOK * HID;     // 2048*4096
  unsigned short* sWb = tA  + (long)TOK * HID;     // 32000*4096
  unsigned short* tWb = sWb + (long)VOC * HID;     // 32000*4096
  unsigned short* sL  = tWb + (long)VOC * HID;     // 2048*32000
  unsigned short* tL  = sL  + (long)TOK * VOC;     // 2048*32000
  float2* ppS = (float2*)(tL + (long)TOK * VOC);   // 2048*125 float2
  float2* ppT = ppS + (long)TOK * NNT;             // 2048*125 float2

  cast_all<<<2048, 256, 0, stream>>>(sIn, sA, (long)TOK * HID,
                                     tIn, tA, (long)TOK * HID,
                                     sW, sWb, (long)VOC * HID,
                                     tW, tWb, (long)VOC * HID,
                                     out);

  const int nblk = 2 * (TOK / 256) * (VOC / 256);  // 2000: student + teacher
  gemm256<<<nblk, 512, 0, stream>>>(sA, sWb, sL, ppS, tA, tWb, tL, ppT);

  jsd_kernel<<<TOK, 256, 0, stream>>>(sL, tL, ppS, ppT, out);
}

// Round 14
// 1238.783 us; speedup vs baseline: 1.0212x; 1.0212x over previous
//
#include <hip/hip_runtime.h>
#include <stdint.h>

#define TOK 2048
#define HID 4096
#define VOC 32000
#define NKT (HID / 64)  // 64 K-tiles of BK=64
#define NNT (VOC / 256) // 125 N-tiles
#define MREF 16.0f      // fixed LSE reference: exp(z-16) safe for |z| << 70

typedef __attribute__((ext_vector_type(4))) float f32x4;
typedef __attribute__((ext_vector_type(8))) short bf16x8;
typedef __attribute__((ext_vector_type(8))) unsigned short u16x8;

__device__ __forceinline__ float bf2f(unsigned short u) {
  return __uint_as_float(((unsigned int)u) << 16);
}
__device__ __forceinline__ unsigned short f2bf(float f) {
  unsigned int u = __float_as_uint(f);
  u += 0x7FFFu + ((u >> 16) & 1u);  // round-to-nearest-even
  return (unsigned short)(u >> 16);
}

// ---------------- all four casts in one launch (4 grid-stride regions) ----------------
__device__ __forceinline__ void cast8(const float* __restrict__ in,
                                      unsigned short* __restrict__ out) {
  const float4 v0 = *(const float4*)(in);
  const float4 v1 = *(const float4*)(in + 4);
  union { ushort s[8]; uint4 u; } o;
  o.s[0] = f2bf(v0.x); o.s[1] = f2bf(v0.y); o.s[2] = f2bf(v0.z); o.s[3] = f2bf(v0.w);
  o.s[4] = f2bf(v1.x); o.s[5] = f2bf(v1.y); o.s[6] = f2bf(v1.z); o.s[7] = f2bf(v1.w);
  *(uint4*)(out) = o.u;
}

__global__ __launch_bounds__(256) void cast_all(const float* __restrict__ a, unsigned short* __restrict__ oa, long na,
                                                const float* __restrict__ b, unsigned short* __restrict__ ob, long nb,
                                                const float* __restrict__ c, unsigned short* __restrict__ oc, long nc,
                                                const float* __restrict__ d, unsigned short* __restrict__ od, long nd,
                                                float* __restrict__ out0) {
  if (blockIdx.x == 0 && threadIdx.x == 0) out0[0] = 0.f;  // init for jsd atomicAdd
  const long base = ((long)blockIdx.x * 256 + threadIdx.x) * 8;
  const long stride = (long)gridDim.x * 256 * 8;
  for (long i = base; i < na; i += stride) cast8(a + i, oa + i);
  for (long i = base; i < nb; i += stride) cast8(b + i, ob + i);
  for (long i = base; i < nc; i += stride) cast8(c + i, oc + i);
  for (long i = base; i < nd; i += stride) cast8(d + i, od + i);
}

// ---------------- async global -> LDS (16B/lane) ----------------
__device__ __forceinline__ void gload_lds16(const void* g, void* l) {
  __builtin_amdgcn_global_load_lds(
      (const __attribute__((address_space(1))) unsigned int*)(uintptr_t)g,
      (__attribute__((address_space(3))) unsigned int*)(uintptr_t)l,
      16, 0, 0);
}

// ---------------- dual 256x256 bf16 GEMM (one dispatch) + fixed-ref LSE epilogue ----
// Blocks 0..999 (after XCD swizzle) -> student, 1000..1999 -> teacher.
// K-loop = r10/r11/r12 measured-best schedule (stageB AFTER the ds_read burst,
// overlapping the 48-MFMA cluster — r13's top-of-tile hoist measured -25us, reverted):
// ds_reads | stageB(u+1) | q00,q10,q11 | lgkm0+bar | stageA(u+2) | q01 (reg-only) |
// vmcnt(4)+bar.
__global__ __launch_bounds__(512, 2) void gemm256(const unsigned short* __restrict__ A0,
                                                  const unsigned short* __restrict__ B0,
                                                  unsigned short* __restrict__ C0,
                                                  float2* __restrict__ pp0,
                                                  const unsigned short* __restrict__ A1,
                                                  const unsigned short* __restrict__ B1,
                                                  unsigned short* __restrict__ C1,
                                                  float2* __restrict__ pp1) {
  __shared__ unsigned short As[2][2][128 * 64];
  __shared__ unsigned short Bs[2][2][128 * 64];
  const int tid = threadIdx.x;
  const int w = tid >> 6;
  const int l = tid & 63;
  const int wr = w >> 2;   // 0..1 (M half)
  const int wc = w & 3;    // 0..3 (N quarter)

  // T1: XCD swizzle over the merged 2000-block grid (2000 % 8 == 0).
  const int bid = blockIdx.x;
  const int cpx = gridDim.x >> 3;                 // 250
  int swz = (bid & 7) * cpx + (bid >> 3);
  const int which = swz >= (TOK / 256) * NNT;     // >= 1000 -> teacher
  if (which) swz -= (TOK / 256) * NNT;
  const int mt = swz & 7;                         // 8 M-tiles
  const int nt = swz >> 3;                        // 125 N-tiles

  const unsigned short* __restrict__ A = which ? A1 : A0;
  const unsigned short* __restrict__ B = which ? B1 : B0;
  unsigned short* __restrict__ C = which ? C1 : C0;
  float2* __restrict__ pp = which ? pp1 : pp0;

  const size_t Abase = (size_t)mt * 256 * HID;
  const size_t Bbase = (size_t)nt * 256 * HID;

  f32x4 acc[8][4] = {};

  const int r8 = l >> 3;
  const int scol = ((l & 7) ^ r8) << 3;  // swizzled source column (elements)

  auto stageA = [&](int half, int v) {
    const unsigned short* src = A + Abase + (size_t)half * 128 * HID + (size_t)v * 64 + scol;
#pragma unroll
    for (int i = 0; i < 2; ++i) {
      const int c = 2 * w + i;
      gload_lds16(src + (size_t)(c * 8 + r8) * HID, &As[v & 1][half][c * 512]);
    }
  };
  auto stageB = [&](int half, int v) {
    const unsigned short* src = B + Bbase + (size_t)half * 128 * HID + (size_t)v * 64 + scol;
#pragma unroll
    for (int i = 0; i < 2; ++i) {
      const int c = 2 * w + i;
      gload_lds16(src + (size_t)(c * 8 + r8) * HID, &Bs[v & 1][half][c * 512]);
    }
  };

  // prologue: tile0 all halves + tile1 A halves; retire tile0's 8 (keep A(1) in flight)
  stageA(0, 0); stageA(1, 0); stageB(0, 0); stageB(1, 0);
  stageA(0, 1); stageA(1, 1);
  asm volatile("s_waitcnt vmcnt(4)" ::: "memory");
  __builtin_amdgcn_s_barrier();

  const int lr = l & 15;
  const int c0 = ((l >> 4) << 4) ^ ((lr & 7) << 4);  // byte col for kk=0
  const int c1 = c0 ^ 64;                            // byte col for kk=32
  const int brow = (wc & 1) * 64;                    // wave's N-row base in its B half

#pragma unroll 2
  for (int u = 0; u < NKT; ++u) {
    const int cur = u & 1;
    const char* Ah = (const char*)&As[cur][wr][0];
    const char* Bh = (const char*)&Bs[cur][wc >> 1][0];
    bf16x8 a0[8], a1[8], b0[4], b1[4];

    // ---- issue all 24 ds_reads (compiler schedules + counted auto-lgkmcnt) ----
#pragma unroll
    for (int mf = 0; mf < 4; ++mf) {
      const int rb = (mf * 16 + lr) << 7;
      a0[2 * mf]     = *(const bf16x8*)(Ah + rb + c0);
      a0[2 * mf + 1] = *(const bf16x8*)(Ah + rb + c1);
    }
#pragma unroll
    for (int nf = 0; nf < 2; ++nf) {
      const int rb = (brow + nf * 16 + lr) << 7;
      b0[2 * nf]     = *(const bf16x8*)(Bh + rb + c0);
      b0[2 * nf + 1] = *(const bf16x8*)(Bh + rb + c1);
    }
#pragma unroll
    for (int mf = 0; mf < 4; ++mf) {
      const int rb = ((mf + 4) * 16 + lr) << 7;
      a1[2 * mf]     = *(const bf16x8*)(Ah + rb + c0);
      a1[2 * mf + 1] = *(const bf16x8*)(Ah + rb + c1);
    }
#pragma unroll
    for (int nf = 0; nf < 2; ++nf) {
      const int rb = (brow + (nf + 2) * 16 + lr) << 7;
      b1[2 * nf]     = *(const bf16x8*)(Bh + rb + c0);
      b1[2 * nf + 1] = *(const bf16x8*)(Bh + rb + c1);
    }

    // stage B(u+1) into buf cur^1 — issue overlaps the 48-MFMA cluster
    if (u + 1 < NKT) { stageB(0, u + 1); stageB(1, u + 1); }

    __builtin_amdgcn_s_setprio(1);
    // q(0,0), q(1,0), q(1,1): 48 MFMA
#pragma unroll
    for (int mf = 0; mf < 4; ++mf)
#pragma unroll
      for (int nf = 0; nf < 2; ++nf) {
        acc[mf][nf] = __builtin_amdgcn_mfma_f32_16x16x32_bf16(a0[2 * mf], b0[2 * nf], acc[mf][nf], 0, 0, 0);
        acc[mf][nf] = __builtin_amdgcn_mfma_f32_16x16x32_bf16(a0[2 * mf + 1], b0[2 * nf + 1], acc[mf][nf], 0, 0, 0);
      }
#pragma unroll
    for (int mf = 0; mf < 4; ++mf)
#pragma unroll
      for (int nf = 0; nf < 2; ++nf) {
        acc[4 + mf][nf] = __builtin_amdgcn_mfma_f32_16x16x32_bf16(a1[2 * mf], b0[2 * nf], acc[4 + mf][nf], 0, 0, 0);
        acc[4 + mf][nf] = __builtin_amdgcn_mfma_f32_16x16x32_bf16(a1[2 * mf + 1], b0[2 * nf + 1], acc[4 + mf][nf], 0, 0, 0);
      }
#pragma unroll
    for (int mf = 0; mf < 4; ++mf)
#pragma unroll
      for (int nf = 0; nf < 2; ++nf) {
        acc[4 + mf][2 + nf] = __builtin_amdgcn_mfma_f32_16x16x32_bf16(a1[2 * mf], b1[2 * nf], acc[4 + mf][2 + nf], 0, 0, 0);
        acc[4 + mf][2 + nf] = __builtin_amdgcn_mfma_f32_16x16x32_bf16(a1[2 * mf + 1], b1[2 * nf + 1], acc[4 + mf][2 + nf], 0, 0, 0);
      }
    __builtin_amdgcn_s_setprio(0);

    // all reads of this tile's buffers drained chip-wide before stageA(u+2)
    asm volatile("s_waitcnt lgkmcnt(0)" ::: "memory");
    __builtin_amdgcn_s_barrier();

    if (u + 2 < NKT) { stageA(0, u + 2); stageA(1, u + 2); }

    __builtin_amdgcn_s_setprio(1);
    // q(0,1): register-only (a0, b1 held) — covers stage-issue + vmcnt shadow
#pragma unroll
    for (int mf = 0; mf < 4; ++mf)
#pragma unroll
      for (int nf = 0; nf < 2; ++nf) {
        acc[mf][2 + nf] = __builtin_amdgcn_mfma_f32_16x16x32_bf16(a0[2 * mf], b1[2 * nf], acc[mf][2 + nf], 0, 0, 0);
        acc[mf][2 + nf] = __builtin_amdgcn_mfma_f32_16x16x32_bf16(a0[2 * mf + 1], b1[2 * nf + 1], acc[mf][2 + nf], 0, 0, 0);
      }
    __builtin_amdgcn_s_setprio(0);

    if (u + 2 < NKT) {
      asm volatile("s_waitcnt vmcnt(4)" ::: "memory");  // retire A(u+1)+B(u+1), keep A(u+2)
      __builtin_amdgcn_s_barrier();
    } else if (u + 1 < NKT) {
      asm volatile("s_waitcnt vmcnt(0)" ::: "memory");  // u=62: drain A(63)+B(63)
      __builtin_amdgcn_s_barrier();
    }
  }

  // ---- epilogue: C write + fixed-ref row-sum of exp(z-MREF), fused ----
  __syncthreads();  // all K-loop LDS reads done; reuse As as reduction scratch
  float* red = (float*)&As[0][0][0];  // [256 rows][stride 5] (pad -> conflict-free)
  const int lg = (l >> 4) * 4;
#pragma unroll
  for (int mf = 0; mf < 8; ++mf)
#pragma unroll
    for (int r = 0; r < 4; ++r) {
      const int rowl = wr * 128 + mf * 16 + lg + r;
      const int row = mt * 256 + rowl;
      float vsum = 0.f;
#pragma unroll
      for (int nf = 0; nf < 4; ++nf) {
        const unsigned short cb = f2bf(acc[mf][nf][r]);
        C[(size_t)row * VOC + nt * 256 + wc * 64 + nf * 16 + lr] = cb;
        vsum += __expf(bf2f(cb) - MREF);
      }
#pragma unroll
      for (int off = 1; off < 16; off <<= 1) vsum += __shfl_xor(vsum, off);
      if (lr == 0) red[rowl * 5 + wc] = vsum;
    }
  __syncthreads();
  if (tid < 256) {
    const float s = red[tid * 5] + red[tid * 5 + 1] + red[tid * 5 + 2] + red[tid * 5 + 3];
    pp[(size_t)(mt * 256 + tid) * NNT + nt] = make_float2(MREF, s);
  }
}

// ---------------- per-token JSD (single pass) + direct atomic accumulation ----------------
__global__ __launch_bounds__(256) void jsd_kernel(const unsigned short* __restrict__ SL,
                                                  const unsigned short* __restrict__ TL,
                                                  const float2* __restrict__ ppS,
                                                  const float2* __restrict__ ppT,
                                                  float* __restrict__ out) {
  const int t = blockIdx.x;
  const int tid = threadIdx.x;
  const unsigned short* srow = SL + (size_t)t * VOC;
  const unsigned short* trow = TL + (size_t)t * VOC;

  // all partial maxima are MREF -> exact additive merge, no exp chains
  float ss = 0.f, st = 0.f;
  if (tid < NNT) {
    ss = ppS[(size_t)t * NNT + tid].y;
    st = ppT[(size_t)t * NNT + tid].y;
  }
#pragma unroll
  for (int off = 32; off > 0; off >>= 1) {
    ss += __shfl_xor(ss, off);
    st += __shfl_xor(st, off);
  }
  __shared__ float red[4][2];
  const int w = tid >> 6;
  if ((tid & 63) == 0) { red[w][0] = ss; red[w][1] = st; }
  __syncthreads();
  const float Ss = red[0][0] + red[1][0] + red[2][0] + red[3][0];
  const float St = red[0][1] + red[1][1] + red[2][1] + red[3][1];
  const float logZs = MREF + __logf(Ss);
  const float logZt = MREF + __logf(St);

  // single pass: jsd = 0.5*[p*(lp-lm) + q*(lq-lm)], lm = log(0.5)+logaddexp(lp,lq)
  float acc = 0.f;
  for (int c = tid; c < VOC / 8; c += 256) {
    u16x8 vs = *(const u16x8*)(srow + c * 8);
    u16x8 vt = *(const u16x8*)(trow + c * 8);
#pragma unroll
    for (int j = 0; j < 8; ++j) {
      float lq = bf2f(vs[j]) - logZs;
      float lp = bf2f(vt[j]) - logZt;
      float mx = fmaxf(lp, lq);
      float d = fabsf(lp - lq);
      float lm = mx + __logf(1.f + __expf(-d)) - 0.69314718f;
      acc += __expf(lp) * (lp - lm) + __expf(lq) * (lq - lm);
    }
  }
  acc *= 0.5f;
#pragma unroll
  for (int off = 32; off > 0; off >>= 1) acc += __shfl_xor(acc, off);
  __shared__ float red2[4];
  if ((tid & 63) == 0) red2[w] = acc;
  __syncthreads();
  if (tid == 0)
    atomicAdd(out, (red2[0] + red2[1] + red2[2] + red2[3]) * (1.0f / TOK));
}

// ---------------- launch ----------------
extern "C" void kernel_launch(void* const* d_in, const int* in_sizes, int n_in,
                              void* d_out, int out_size, void* d_ws, size_t ws_size,
                              hipStream_t stream) {
  const float* sIn = (const float*)d_in[0];
  const float* tIn = (const float*)d_in[1];
  const float* sW  = (const float*)d_in[2];
  const float* tW  = (const float*)d_in[3];
  float* out = (float*)d_out;

  unsigned short* ws = (unsigned short*)d_ws;
  unsigned short* sA  = ws;                        // 2048*4096 bf16
  unsigned short* tA  = sA  + (long)TOK * HID;     // 2048*4096
  unsigned short* sWb = tA  + (long)TOK * HID;     // 32000*4096
  unsigned short* tWb = sWb + (long)VOC * HID;     // 32000*4096
  unsigned short* sL  = tWb + (long)VOC * HID;     // 2048*32000
  unsigned short* tL  = sL  + (long)TOK * VOC;     // 2048*32000
  float2* ppS = (float2*)(tL + (long)TOK * VOC);   // 2048*125 float2
  float2* ppT = ppS + (long)TOK * NNT;             // 2048*125 float2

  cast_all<<<2048, 256, 0, stream>>>(sIn, sA, (long)TOK * HID,
                                     tIn, tA, (long)TOK * HID,
                                     sW, sWb, (long)VOC * HID,
                                     tW, tWb, (long)VOC * HID,
                                     out);

  const int nblk = 2 * (TOK / 256) * (VOC / 256);  // 2000: student + teacher
  gemm256<<<nblk, 512, 0, stream>>>(sA, sWb, sL, ppS, tA, tWb, tL, ppT);

  jsd_kernel<<<TOK, 256, 0, stream>>>(sL, tL, ppS, ppT, out);
}